// Round 7
// baseline (254.905 us; speedup 1.0000x reference)
//
#include <hip/hip_runtime.h>
#include <cstdint>

typedef unsigned short u16;
typedef unsigned int u32;
typedef __attribute__((ext_vector_type(8))) short bf16x8;   // 8 bf16 in 4 VGPRs
typedef __attribute__((ext_vector_type(4))) float f32x4;
typedef __attribute__((ext_vector_type(16))) float f32x16;
typedef __attribute__((ext_vector_type(2))) unsigned int u32x2;

#if __has_builtin(__builtin_amdgcn_exp2f)
#define EXP2(x) __builtin_amdgcn_exp2f(x)
#else
#define EXP2(x) exp2f(x)
#endif

__device__ __forceinline__ u16 f2bf(float f) {  // RNE
  unsigned u = __float_as_uint(f);
  u += 0x7fffu + ((u >> 16) & 1u);
  return (u16)(u >> 16);
}
__device__ __forceinline__ u32 pk_bf16(float lo, float hi) {  // RNE pack
#if __has_builtin(__builtin_amdgcn_cvt_pk_bf16_f32)
  auto r = __builtin_amdgcn_cvt_pk_bf16_f32(lo, hi);
  return __builtin_bit_cast(u32, r);
#else
  u32 a = __float_as_uint(lo), b = __float_as_uint(hi);
  a += 0x7fffu + ((a >> 16) & 1u);
  b += 0x7fffu + ((b >> 16) & 1u);
  return (a >> 16) | (b & 0xffff0000u);
#endif
}

// permlane32_swap: r0 = {x.lo | y.lo-from-partner}, r1 = {x.hi-from-partner | y.hi}
__device__ __forceinline__ void plane32swap(u32 x, u32 y, u32& r0, u32& r1) {
#if __has_builtin(__builtin_amdgcn_permlane32_swap)
  u32x2 r = __builtin_amdgcn_permlane32_swap(x, y, false, false);
  r0 = r[0]; r1 = r[1];
#else
  const u32 xs = (u32)__shfl_xor((int)x, 32, 64);
  const u32 ys = (u32)__shfl_xor((int)y, 32, 64);
  const bool hi = (threadIdx.x & 32) != 0;
  r0 = hi ? ys : x;
  r1 = hi ? y : xs;
#endif
}

// async global->LDS, 16B per lane. LDS dest must be wave-uniform base + lane*16.
__device__ __forceinline__ void async_load16(const void* g, void* l) {
  typedef const __attribute__((address_space(1))) void* gp_t;
  typedef __attribute__((address_space(3))) void* lp_t;
  __builtin_amdgcn_global_load_lds((gp_t)(uintptr_t)g, (lp_t)(uintptr_t)l, 16, 0, 0);
}

// ------- fused preprocess: x f32->bf16 copy (blocks [0,2048)) + both weight
//         transposes (blocks [2048,3072)) in ONE launch -------
__global__ __launch_bounds__(256) void preprocess(
    const float* __restrict__ x, u16* __restrict__ xb,
    const float* __restrict__ wqkv, u16* __restrict__ dqkv,
    const float* __restrict__ wout, u16* __restrict__ dout)
{
  __shared__ u16 tile[64][65];
  const int t = threadIdx.x;
  const int bx = blockIdx.x;
  if (bx < 2048) {
    const size_t i = ((size_t)bx * 256 + t) * 8;
    const float4 a = *(const float4*)(x + i);
    const float4 b = *(const float4*)(x + i + 4);
    union { u16 u[8]; bf16x8 v; } p;
    p.u[0] = f2bf(a.x); p.u[1] = f2bf(a.y); p.u[2] = f2bf(a.z); p.u[3] = f2bf(a.w);
    p.u[4] = f2bf(b.x); p.u[5] = f2bf(b.y); p.u[6] = f2bf(b.z); p.u[7] = f2bf(b.w);
    *(bf16x8*)(xb + i) = p.v;
    return;
  }
  const int tb = bx - 2048;            // 0..1023
  const int bxx = tb & 63, byy = tb >> 6;
  const bool isOut = bxx >= 48;
  const float* src = isOut ? wout : wqkv;
  u16* dst = isOut ? dout : dqkv;
  const int cols = isOut ? 1024 : 3072;
  const int rows = 1024;
  const int tc = (isOut ? (bxx - 48) : bxx) * 64;
  const int tr = byy * 64;
  const int r = t >> 2, c0 = (t & 3) * 16;
  const float* sp = src + (size_t)(tr + r) * cols + tc + c0;
#pragma unroll
  for (int i = 0; i < 16; i += 4) {
    const float4 v = *(const float4*)(sp + i);
    tile[r][c0 + i + 0] = f2bf(v.x);
    tile[r][c0 + i + 1] = f2bf(v.y);
    tile[r][c0 + i + 2] = f2bf(v.z);
    tile[r][c0 + i + 3] = f2bf(v.w);
  }
  __syncthreads();
  u16* dp = dst + (size_t)(tc + r) * rows + tr + c0;
#pragma unroll
  for (int i = 0; i < 16; ++i) dp[i] = tile[c0 + i][r];
}

// ---------------- QKV GEMM v3: double-buffered + direct-Vt epilogue ----------------
__global__ __launch_bounds__(256) void gemm_qkv(
    const u16* __restrict__ A, const u16* __restrict__ Bt, const float* __restrict__ bias,
    u16* __restrict__ Qp, u16* __restrict__ Kp, u16* __restrict__ Vtp)
{
  const int Kd = 1024;
  __shared__ __align__(16) u16 As[2][128 * 32];
  __shared__ __align__(16) u16 Bs[2][128 * 32];
  const int t = threadIdx.x;
  const int lane = t & 63, wave = t >> 6;
  const int quad = lane >> 4, m16 = lane & 15;
  const int mb = blockIdx.y * 128, nb = blockIdx.x * 128;
  const int wr = (wave & 1) * 64, wc = (wave >> 1) * 64;

  // wave-uniform segment decode
  const int seg = (nb + wc) >> 6;          // = h*3 + which
  const int h = seg / 3;
  const int which = seg - 3 * h;
  const bool isV = (which == 2);

  const int srow = t >> 2;
  const int scol = (t & 3) * 8;
  const u16* Ag0 = A + (size_t)(mb + srow) * Kd + scol;
  const u16* Ag1 = Ag0 + (size_t)64 * Kd;
  const u16* Bg0 = Bt + (size_t)(nb + srow) * Kd + scol;
  const u16* Bg1 = Bg0 + (size_t)64 * Kd;
  const int aoff = t * 8;

  f32x4 acc[4][4] = {};

#define GPRE(k0, B)                                                          \
  do {                                                                       \
    async_load16(Ag0 + (k0), &As[B][aoff]);                                  \
    async_load16(Ag1 + (k0), &As[B][aoff + 2048]);                           \
    async_load16(Bg0 + (k0), &Bs[B][aoff]);                                  \
    async_load16(Bg1 + (k0), &Bs[B][aoff + 2048]);                           \
  } while (0)

#define GSTEP(B)                                                             \
  do {                                                                       \
    bf16x8 af[4], bfr[4];                                                    \
    _Pragma("unroll")                                                        \
    for (int i = 0; i < 4; ++i)                                              \
      af[i] = *(const bf16x8*)(&As[B][(wr + i * 16 + m16) * 32 + quad * 8]); \
    _Pragma("unroll")                                                        \
    for (int i = 0; i < 4; ++i)                                              \
      bfr[i] = *(const bf16x8*)(&Bs[B][(wc + i * 16 + m16) * 32 + quad * 8]); \
    if (isV) {                                                               \
      _Pragma("unroll")                                                      \
      for (int i = 0; i < 4; ++i)                                            \
        _Pragma("unroll")                                                    \
        for (int j = 0; j < 4; ++j)                                          \
          acc[i][j] = __builtin_amdgcn_mfma_f32_16x16x32_bf16(bfr[i], af[j], acc[i][j], 0, 0, 0); \
    } else {                                                                 \
      _Pragma("unroll")                                                      \
      for (int i = 0; i < 4; ++i)                                            \
        _Pragma("unroll")                                                    \
        for (int j = 0; j < 4; ++j)                                          \
          acc[i][j] = __builtin_amdgcn_mfma_f32_16x16x32_bf16(af[i], bfr[j], acc[i][j], 0, 0, 0); \
    }                                                                        \
  } while (0)

  GPRE(0, 0);
  __syncthreads();
  for (int k0 = 0; k0 < Kd; k0 += 64) {
    GPRE(k0 + 32, 1);                // always valid (k0+32 <= 992)
    GSTEP(0);
    __syncthreads();
    if (k0 + 64 < Kd) GPRE(k0 + 64, 0);
    GSTEP(1);
    __syncthreads();
  }
#undef GPRE
#undef GSTEP

  const int b = mb >> 11;                  // block rows stay in one batch
  const size_t bh64 = (size_t)((b << 4) | h);

  if (isV) {
    // acc[i][j] = C^T tile: row d = i*16+quad*4+r, col s = mb+wr+j*16+m16
    const int sIbase = (mb & 2047) + wr;
    u16* dstV = Vtp + bh64 * 64 * 2048;
#pragma unroll
    for (int i = 0; i < 4; ++i)
#pragma unroll
      for (int r = 0; r < 4; ++r) {
        const int d = i * 16 + quad * 4 + r;
        const float bv = bias[nb + wc + d];
        u16* rp = dstV + (size_t)d * 2048 + sIbase;
#pragma unroll
        for (int j = 0; j < 4; ++j)
          rp[j * 16 + m16] = f2bf(acc[i][j][r] + bv);
      }
  } else {
    u16* dstP = (which == 0) ? Qp : Kp;
    const float qs = (which == 0) ? 0.18033688011112042f : 1.0f;  // 0.125*log2(e)
#pragma unroll
    for (int j = 0; j < 4; ++j) {
      const int base = nb + wc + j * 16;
      const float bv = bias[base + m16];
      const int d = (base & 63) + m16;     // = j*16 + m16
#pragma unroll
      for (int i = 0; i < 4; ++i)
#pragma unroll
        for (int r = 0; r < 4; ++r) {
          const int row = mb + wr + i * 16 + quad * 4 + r;
          const int sI = row & 2047;
          dstP[(bh64 * 2048 + sI) * 64 + d] = f2bf((acc[i][j][r] + bv) * qs);
        }
    }
  }
}

// ---------------- out-proj GEMM v2: 64x128 tile, double-buffered, 1 barrier/step ---
__global__ __launch_bounds__(256) void gemm_out(
    const u16* __restrict__ A, const u16* __restrict__ Bt, const float* __restrict__ bias,
    float* __restrict__ Outp)
{
  const int Kd = 1024;
  __shared__ __align__(16) u16 As[2][64 * 32];
  __shared__ __align__(16) u16 Bs[2][128 * 32];
  const int t = threadIdx.x;
  const int lane = t & 63, wave = t >> 6;
  const int quad = lane >> 4, m16 = lane & 15;
  const int mb = blockIdx.y * 64, nb = blockIdx.x * 128;
  const int wr = (wave & 1) * 32, wc = (wave >> 1) * 64;

  const int srow = t >> 2;
  const int scol = (t & 3) * 8;
  const u16* Ag0 = A + (size_t)(mb + srow) * Kd + scol;
  const u16* Bg0 = Bt + (size_t)(nb + srow) * Kd + scol;
  const u16* Bg1 = Bg0 + (size_t)64 * Kd;
  const int aoff = t * 8;

  f32x4 acc[2][4] = {};

#define OPRE(k0, B)                                                          \
  do {                                                                       \
    async_load16(Ag0 + (k0), &As[B][aoff]);                                  \
    async_load16(Bg0 + (k0), &Bs[B][aoff]);                                  \
    async_load16(Bg1 + (k0), &Bs[B][aoff + 2048]);                           \
  } while (0)

#define OSTEP(B)                                                             \
  do {                                                                       \
    bf16x8 af[2], bfr[4];                                                    \
    _Pragma("unroll")                                                        \
    for (int i = 0; i < 2; ++i)                                              \
      af[i] = *(const bf16x8*)(&As[B][(wr + i * 16 + m16) * 32 + quad * 8]); \
    _Pragma("unroll")                                                        \
    for (int j = 0; j < 4; ++j)                                              \
      bfr[j] = *(const bf16x8*)(&Bs[B][(wc + j * 16 + m16) * 32 + quad * 8]); \
    _Pragma("unroll")                                                        \
    for (int i = 0; i < 2; ++i)                                              \
      _Pragma("unroll")                                                      \
      for (int j = 0; j < 4; ++j)                                            \
        acc[i][j] = __builtin_amdgcn_mfma_f32_16x16x32_bf16(af[i], bfr[j], acc[i][j], 0, 0, 0); \
  } while (0)

  OPRE(0, 0);
  __syncthreads();
  for (int k0 = 0; k0 < Kd; k0 += 64) {
    OPRE(k0 + 32, 1);
    OSTEP(0);
    __syncthreads();
    if (k0 + 64 < Kd) OPRE(k0 + 64, 0);
    OSTEP(1);
    __syncthreads();
  }
#undef OPRE
#undef OSTEP

#pragma unroll
  for (int j = 0; j < 4; ++j) {
    const int col = nb + wc + j * 16 + m16;
    const float bv = bias[col];
#pragma unroll
    for (int i = 0; i < 2; ++i)
#pragma unroll
      for (int r = 0; r < 4; ++r) {
        const int row = mb + wr + i * 16 + quad * 4 + r;
        Outp[(size_t)row * 1024 + col] = acc[i][j][r] + bv;
      }
  }
}

// -------- flash attention v11: ZERO-LDS streaming. 32x32 swapped-QKT,
//          in-register P (cvt_pk + permlane32_swap). K/V fragments loaded
//          DIRECTLY global->VGPR (K/V are L2-resident: 512KB/head, ~4 heads/XCD
//          with this bh mapping). No __shared__, no barriers -- each wave is an
//          independent stream. K double-buffered (kA/kB, 1 tile ahead); V
//          single-buffered, issued at step-top so QK^T+softmax hides its L2
//          latency. All register indexing static (unroll-2 over tiles). -------
__global__ __launch_bounds__(256) void flash_attn(
    const u16* __restrict__ Q, const u16* __restrict__ K, const u16* __restrict__ Vt,
    u16* __restrict__ O)
{
  const int S = 2048;
  const int t = threadIdx.x;
  const int lane = t & 63, w = t >> 6;
  const int l31 = lane & 31, hi = lane >> 5;

  const int f = blockIdx.x;
  const int wi = f >> 3;                 // 0..63
  const int bh = (f & 7) + 8 * (wi & 3); // consecutive blocks -> different heads
  const int q0 = (wi >> 2) * 128;        // (XCD round-robin => ~4 heads per XCD L2)

  const u16* Qb = Q + (size_t)bh * S * 64;
  const u16* Kb = K + (size_t)bh * S * 64;
  const u16* Vb = Vt + (size_t)bh * 64 * S;

  // Q as QK^T B-operand: B[n=q][k=d], lane n = l31, k-chunk dc: d = dc*16 + hi*8 + e
  bf16x8 qf[4];
#pragma unroll
  for (int dc = 0; dc < 4; ++dc)
    qf[dc] = *(const bf16x8*)(Qb + (size_t)(q0 + w * 32 + l31) * 64 + dc * 16 + hi * 8);

  // per-lane fragment base pointers (un-swizzled: direct fragment addresses)
  // K frag (tile, kt, dc): Kp0 + (tile*64 + kt*32)*64 + dc*16   [row l31, +hi*8]
  // V frag (tile, dt, c):  Vp0 + dt*32*S + tile*64 + c*16       [row l31, +hi*8]
  const u16* const Kp0 = Kb + (size_t)l31 * 64 + hi * 8;
  const u16* const Vp0 = Vb + (size_t)l31 * S + hi * 8;

  f32x16 ot[2] = {};
  float lr4[4] = {0.f, 0.f, 0.f, 0.f};
  bf16x8 kA[8], kB[8], vv[8], pa[4];

#define LOADK(ARR, tile)                                                     \
  do {                                                                       \
    _Pragma("unroll")                                                        \
    for (int kt = 0; kt < 2; ++kt)                                           \
      _Pragma("unroll")                                                      \
      for (int dc = 0; dc < 4; ++dc)                                         \
        ARR[kt * 4 + dc] = *(const bf16x8*)(Kp0 + (size_t)((tile) * 64 + kt * 32) * 64 + dc * 16); \
  } while (0)

#define LOADV(tile)                                                          \
  do {                                                                       \
    _Pragma("unroll")                                                        \
    for (int dt = 0; dt < 2; ++dt)                                           \
      _Pragma("unroll")                                                      \
      for (int c = 0; c < 4; ++c)                                            \
        vv[dt * 4 + c] = *(const bf16x8*)(Vp0 + (size_t)dt * 32 * S + (tile) * 64 + c * 16); \
  } while (0)

#define QKT_SM(KARR)                                                         \
  do {                                                                       \
    _Pragma("unroll")                                                        \
    for (int kt = 0; kt < 2; ++kt) {                                         \
      f32x16 st = {0.f,0.f,0.f,0.f, 0.f,0.f,0.f,0.f,                         \
                   0.f,0.f,0.f,0.f, 0.f,0.f,0.f,0.f};                        \
      _Pragma("unroll")                                                      \
      for (int dc = 0; dc < 4; ++dc)                                         \
        st = __builtin_amdgcn_mfma_f32_32x32x16_bf16(KARR[kt * 4 + dc], qf[dc], st, 0, 0, 0); \
      float p[16];                                                           \
      _Pragma("unroll")                                                      \
      for (int r = 0; r < 16; ++r) { p[r] = EXP2(st[r]); lr4[r & 3] += p[r]; } \
      _Pragma("unroll")                                                      \
      for (int cc = 0; cc < 2; ++cc) {                                       \
        union { u32 u[4]; bf16x8 v; } fr;                                    \
        _Pragma("unroll")                                                    \
        for (int i = 0; i < 2; ++i) {                                        \
          const u32 xx = pk_bf16(p[8 * cc + 2 * i + 0], p[8 * cc + 2 * i + 1]); \
          const u32 yy = pk_bf16(p[8 * cc + 2 * i + 4], p[8 * cc + 2 * i + 5]); \
          u32 r0, r1;                                                        \
          plane32swap(xx, yy, r0, r1);                                       \
          fr.u[i] = r0; fr.u[2 + i] = r1;                                    \
        }                                                                    \
        pa[kt * 2 + cc] = fr.v;                                              \
      }                                                                      \
    }                                                                        \
  } while (0)

#define PV()                                                                 \
  do {                                                                       \
    _Pragma("unroll")                                                        \
    for (int c = 0; c < 4; ++c)                                              \
      _Pragma("unroll")                                                      \
      for (int dt = 0; dt < 2; ++dt)                                         \
        ot[dt] = __builtin_amdgcn_mfma_f32_32x32x16_bf16(vv[dt * 4 + c], pa[c], ot[dt], 0, 0, 0); \
  } while (0)

  LOADK(kA, 0);
  for (int tp = 0; tp < 32; tp += 2) {
    // even tile tp: compute from kA, prefetch K(tp+1) into kB
    LOADV(tp);
    LOADK(kB, tp + 1);                  // tp+1 <= 31 always
    QKT_SM(kA);
    PV();
    // odd tile tp+1: compute from kB, prefetch K(tp+2) into kA
    LOADV(tp + 1);
    if (tp + 2 < 32) LOADK(kA, tp + 2);
    QKT_SM(kB);
    PV();
  }
#undef LOADK
#undef LOADV
#undef QKT_SM
#undef PV

  // row q = q0 + w*32 + l31 lives in this lane's accumulator column; the two
  // hi-halves hold complementary kv subsets -> one xor-32 combine for l.
  float l = lr4[0] + lr4[1] + lr4[2] + lr4[3];
  l += __shfl_xor(l, 32, 64);
  const float inv = 1.0f / l;
  const int b = bh >> 4, h = bh & 15;
  const int q = q0 + w * 32 + l31;
  u16* base = O + ((size_t)b * 2048 + q) * 1024 + h * 64;
#pragma unroll
  for (int dt = 0; dt < 2; ++dt)
#pragma unroll
    for (int g4 = 0; g4 < 4; ++g4) {
      // reg r=4*g4+j -> d = dt*32 + 8*g4 + 4*hi + j
      const u32 lo = pk_bf16(ot[dt][4 * g4 + 0] * inv, ot[dt][4 * g4 + 1] * inv);
      const u32 h2 = pk_bf16(ot[dt][4 * g4 + 2] * inv, ot[dt][4 * g4 + 3] * inv);
      *(uint2*)(base + dt * 32 + 8 * g4 + 4 * hi) = make_uint2(lo, h2);
    }
}

// ---------------- launch ----------------
extern "C" void kernel_launch(void* const* d_in, const int* in_sizes, int n_in,
                              void* d_out, int out_size, void* d_ws, size_t ws_size,
                              hipStream_t stream)
{
  const float* x     = (const float*)d_in[0];   // [2,2048,1024] f32
  const float* w_qkv = (const float*)d_in[1];   // [1024,3072]  f32
  const float* b_qkv = (const float*)d_in[2];   // [3072]       f32
  const float* w_out = (const float*)d_in[3];   // [1024,1024]  f32
  const float* b_out = (const float*)d_in[4];   // [1024]       f32
  float* out = (float*)d_out;                   // [2,2048,1024] f32

  u16* ws     = (u16*)d_ws;
  u16* xb     = ws;                          // [4096][1024] bf16
  u16* WtQKV  = xb + 4194304;                // [3072][1024] bf16
  u16* WtOut  = WtQKV + 3145728;             // [1024][1024] bf16
  u16* Qm     = WtOut + 1048576;             // [B,H,S,64]
  u16* Km     = Qm + 4194304;                // [B,H,S,64]
  u16* Vtm    = Km + 4194304;                // [B,H,64,S]  (written directly by gemm_qkv)
  u16* AO     = Vtm + 4194304;               // [B,S,E] bf16

  preprocess<<<3072, 256, 0, stream>>>(x, xb, w_qkv, WtQKV, w_out, WtOut);
  gemm_qkv<<<dim3(24, 32), 256, 0, stream>>>(xb, WtQKV, b_qkv, Qm, Km, Vtm);
  flash_attn<<<512, 256, 0, stream>>>(Qm, Km, Vtm, AO);
  gemm_out<<<dim3(8, 64), 256, 0, stream>>>(AO, WtOut, b_out, out);
}

// Round 8
// 181.580 us; speedup vs baseline: 1.4038x; 1.4038x over previous
//
#include <hip/hip_runtime.h>
#include <cstdint>

typedef unsigned short u16;
typedef unsigned int u32;
typedef __attribute__((ext_vector_type(8))) short bf16x8;   // 8 bf16 in 4 VGPRs
typedef __attribute__((ext_vector_type(4))) float f32x4;
typedef __attribute__((ext_vector_type(16))) float f32x16;
typedef __attribute__((ext_vector_type(2))) unsigned int u32x2;

#if __has_builtin(__builtin_amdgcn_exp2f)
#define EXP2(x) __builtin_amdgcn_exp2f(x)
#else
#define EXP2(x) exp2f(x)
#endif

__device__ __forceinline__ u16 f2bf(float f) {  // RNE
  unsigned u = __float_as_uint(f);
  u += 0x7fffu + ((u >> 16) & 1u);
  return (u16)(u >> 16);
}
__device__ __forceinline__ u32 pk_bf16(float lo, float hi) {  // RNE pack
#if __has_builtin(__builtin_amdgcn_cvt_pk_bf16_f32)
  auto r = __builtin_amdgcn_cvt_pk_bf16_f32(lo, hi);
  return __builtin_bit_cast(u32, r);
#else
  u32 a = __float_as_uint(lo), b = __float_as_uint(hi);
  a += 0x7fffu + ((a >> 16) & 1u);
  b += 0x7fffu + ((b >> 16) & 1u);
  return (a >> 16) | (b & 0xffff0000u);
#endif
}

// permlane32_swap: r0 = {x.lo | y.lo-from-partner}, r1 = {x.hi-from-partner | y.hi}
__device__ __forceinline__ void plane32swap(u32 x, u32 y, u32& r0, u32& r1) {
#if __has_builtin(__builtin_amdgcn_permlane32_swap)
  u32x2 r = __builtin_amdgcn_permlane32_swap(x, y, false, false);
  r0 = r[0]; r1 = r[1];
#else
  const u32 xs = (u32)__shfl_xor((int)x, 32, 64);
  const u32 ys = (u32)__shfl_xor((int)y, 32, 64);
  const bool hi = (threadIdx.x & 32) != 0;
  r0 = hi ? ys : x;
  r1 = hi ? y : xs;
#endif
}

// async global->LDS, 16B per lane. LDS dest must be wave-uniform base + lane*16.
__device__ __forceinline__ void async_load16(const void* g, void* l) {
  typedef const __attribute__((address_space(1))) void* gp_t;
  typedef __attribute__((address_space(3))) void* lp_t;
  __builtin_amdgcn_global_load_lds((gp_t)(uintptr_t)g, (lp_t)(uintptr_t)l, 16, 0, 0);
}

// ------- fused preprocess: x f32->bf16 copy (blocks [0,2048)) + both weight
//         transposes (blocks [2048,3072)) in ONE launch -------
__global__ __launch_bounds__(256) void preprocess(
    const float* __restrict__ x, u16* __restrict__ xb,
    const float* __restrict__ wqkv, u16* __restrict__ dqkv,
    const float* __restrict__ wout, u16* __restrict__ dout)
{
  __shared__ u16 tile[64][65];
  const int t = threadIdx.x;
  const int bx = blockIdx.x;
  if (bx < 2048) {
    const size_t i = ((size_t)bx * 256 + t) * 8;
    const float4 a = *(const float4*)(x + i);
    const float4 b = *(const float4*)(x + i + 4);
    union { u16 u[8]; bf16x8 v; } p;
    p.u[0] = f2bf(a.x); p.u[1] = f2bf(a.y); p.u[2] = f2bf(a.z); p.u[3] = f2bf(a.w);
    p.u[4] = f2bf(b.x); p.u[5] = f2bf(b.y); p.u[6] = f2bf(b.z); p.u[7] = f2bf(b.w);
    *(bf16x8*)(xb + i) = p.v;
    return;
  }
  const int tb = bx - 2048;            // 0..1023
  const int bxx = tb & 63, byy = tb >> 6;
  const bool isOut = bxx >= 48;
  const float* src = isOut ? wout : wqkv;
  u16* dst = isOut ? dout : dqkv;
  const int cols = isOut ? 1024 : 3072;
  const int rows = 1024;
  const int tc = (isOut ? (bxx - 48) : bxx) * 64;
  const int tr = byy * 64;
  const int r = t >> 2, c0 = (t & 3) * 16;
  const float* sp = src + (size_t)(tr + r) * cols + tc + c0;
#pragma unroll
  for (int i = 0; i < 16; i += 4) {
    const float4 v = *(const float4*)(sp + i);
    tile[r][c0 + i + 0] = f2bf(v.x);
    tile[r][c0 + i + 1] = f2bf(v.y);
    tile[r][c0 + i + 2] = f2bf(v.z);
    tile[r][c0 + i + 3] = f2bf(v.w);
  }
  __syncthreads();
  u16* dp = dst + (size_t)(tc + r) * rows + tr + c0;
#pragma unroll
  for (int i = 0; i < 16; ++i) dp[i] = tile[c0 + i][r];
}

// ---------------- QKV GEMM v3: double-buffered + direct-Vt epilogue ----------------
__global__ __launch_bounds__(256) void gemm_qkv(
    const u16* __restrict__ A, const u16* __restrict__ Bt, const float* __restrict__ bias,
    u16* __restrict__ Qp, u16* __restrict__ Kp, u16* __restrict__ Vtp)
{
  const int Kd = 1024;
  __shared__ __align__(16) u16 As[2][128 * 32];
  __shared__ __align__(16) u16 Bs[2][128 * 32];
  const int t = threadIdx.x;
  const int lane = t & 63, wave = t >> 6;
  const int quad = lane >> 4, m16 = lane & 15;
  const int mb = blockIdx.y * 128, nb = blockIdx.x * 128;
  const int wr = (wave & 1) * 64, wc = (wave >> 1) * 64;

  // wave-uniform segment decode
  const int seg = (nb + wc) >> 6;          // = h*3 + which
  const int h = seg / 3;
  const int which = seg - 3 * h;
  const bool isV = (which == 2);

  const int srow = t >> 2;
  const int scol = (t & 3) * 8;
  const u16* Ag0 = A + (size_t)(mb + srow) * Kd + scol;
  const u16* Ag1 = Ag0 + (size_t)64 * Kd;
  const u16* Bg0 = Bt + (size_t)(nb + srow) * Kd + scol;
  const u16* Bg1 = Bg0 + (size_t)64 * Kd;
  const int aoff = t * 8;

  f32x4 acc[4][4] = {};

#define GPRE(k0, B)                                                          \
  do {                                                                       \
    async_load16(Ag0 + (k0), &As[B][aoff]);                                  \
    async_load16(Ag1 + (k0), &As[B][aoff + 2048]);                           \
    async_load16(Bg0 + (k0), &Bs[B][aoff]);                                  \
    async_load16(Bg1 + (k0), &Bs[B][aoff + 2048]);                           \
  } while (0)

#define GSTEP(B)                                                             \
  do {                                                                       \
    bf16x8 af[4], bfr[4];                                                    \
    _Pragma("unroll")                                                        \
    for (int i = 0; i < 4; ++i)                                              \
      af[i] = *(const bf16x8*)(&As[B][(wr + i * 16 + m16) * 32 + quad * 8]); \
    _Pragma("unroll")                                                        \
    for (int i = 0; i < 4; ++i)                                              \
      bfr[i] = *(const bf16x8*)(&Bs[B][(wc + i * 16 + m16) * 32 + quad * 8]); \
    if (isV) {                                                               \
      _Pragma("unroll")                                                      \
      for (int i = 0; i < 4; ++i)                                            \
        _Pragma("unroll")                                                    \
        for (int j = 0; j < 4; ++j)                                          \
          acc[i][j] = __builtin_amdgcn_mfma_f32_16x16x32_bf16(bfr[i], af[j], acc[i][j], 0, 0, 0); \
    } else {                                                                 \
      _Pragma("unroll")                                                      \
      for (int i = 0; i < 4; ++i)                                            \
        _Pragma("unroll")                                                    \
        for (int j = 0; j < 4; ++j)                                          \
          acc[i][j] = __builtin_amdgcn_mfma_f32_16x16x32_bf16(af[i], bfr[j], acc[i][j], 0, 0, 0); \
    }                                                                        \
  } while (0)

  GPRE(0, 0);
  __syncthreads();
  for (int k0 = 0; k0 < Kd; k0 += 64) {
    GPRE(k0 + 32, 1);                // always valid (k0+32 <= 992)
    GSTEP(0);
    __syncthreads();
    if (k0 + 64 < Kd) GPRE(k0 + 64, 0);
    GSTEP(1);
    __syncthreads();
  }
#undef GPRE
#undef GSTEP

  const int b = mb >> 11;                  // block rows stay in one batch
  const size_t bh64 = (size_t)((b << 4) | h);

  if (isV) {
    // acc[i][j] = C^T tile: row d = i*16+quad*4+r, col s = mb+wr+j*16+m16
    const int sIbase = (mb & 2047) + wr;
    u16* dstV = Vtp + bh64 * 64 * 2048;
#pragma unroll
    for (int i = 0; i < 4; ++i)
#pragma unroll
      for (int r = 0; r < 4; ++r) {
        const int d = i * 16 + quad * 4 + r;
        const float bv = bias[nb + wc + d];
        u16* rp = dstV + (size_t)d * 2048 + sIbase;
#pragma unroll
        for (int j = 0; j < 4; ++j)
          rp[j * 16 + m16] = f2bf(acc[i][j][r] + bv);
      }
  } else {
    u16* dstP = (which == 0) ? Qp : Kp;
    const float qs = (which == 0) ? 0.18033688011112042f : 1.0f;  // 0.125*log2(e)
#pragma unroll
    for (int j = 0; j < 4; ++j) {
      const int base = nb + wc + j * 16;
      const float bv = bias[base + m16];
      const int d = (base & 63) + m16;     // = j*16 + m16
#pragma unroll
      for (int i = 0; i < 4; ++i)
#pragma unroll
        for (int r = 0; r < 4; ++r) {
          const int row = mb + wr + i * 16 + quad * 4 + r;
          const int sI = row & 2047;
          dstP[(bh64 * 2048 + sI) * 64 + d] = f2bf((acc[i][j][r] + bv) * qs);
        }
    }
  }
}

// ---------------- out-proj GEMM v2: 64x128 tile, double-buffered, 1 barrier/step ---
__global__ __launch_bounds__(256) void gemm_out(
    const u16* __restrict__ A, const u16* __restrict__ Bt, const float* __restrict__ bias,
    float* __restrict__ Outp)
{
  const int Kd = 1024;
  __shared__ __align__(16) u16 As[2][64 * 32];
  __shared__ __align__(16) u16 Bs[2][128 * 32];
  const int t = threadIdx.x;
  const int lane = t & 63, wave = t >> 6;
  const int quad = lane >> 4, m16 = lane & 15;
  const int mb = blockIdx.y * 64, nb = blockIdx.x * 128;
  const int wr = (wave & 1) * 32, wc = (wave >> 1) * 64;

  const int srow = t >> 2;
  const int scol = (t & 3) * 8;
  const u16* Ag0 = A + (size_t)(mb + srow) * Kd + scol;
  const u16* Bg0 = Bt + (size_t)(nb + srow) * Kd + scol;
  const u16* Bg1 = Bg0 + (size_t)64 * Kd;
  const int aoff = t * 8;

  f32x4 acc[2][4] = {};

#define OPRE(k0, B)                                                          \
  do {                                                                       \
    async_load16(Ag0 + (k0), &As[B][aoff]);                                  \
    async_load16(Bg0 + (k0), &Bs[B][aoff]);                                  \
    async_load16(Bg1 + (k0), &Bs[B][aoff + 2048]);                           \
  } while (0)

#define OSTEP(B)                                                             \
  do {                                                                       \
    bf16x8 af[2], bfr[4];                                                    \
    _Pragma("unroll")                                                        \
    for (int i = 0; i < 2; ++i)                                              \
      af[i] = *(const bf16x8*)(&As[B][(wr + i * 16 + m16) * 32 + quad * 8]); \
    _Pragma("unroll")                                                        \
    for (int j = 0; j < 4; ++j)                                              \
      bfr[j] = *(const bf16x8*)(&Bs[B][(wc + j * 16 + m16) * 32 + quad * 8]); \
    _Pragma("unroll")                                                        \
    for (int i = 0; i < 2; ++i)                                              \
      _Pragma("unroll")                                                      \
      for (int j = 0; j < 4; ++j)                                            \
        acc[i][j] = __builtin_amdgcn_mfma_f32_16x16x32_bf16(af[i], bfr[j], acc[i][j], 0, 0, 0); \
  } while (0)

  OPRE(0, 0);
  __syncthreads();
  for (int k0 = 0; k0 < Kd; k0 += 64) {
    OPRE(k0 + 32, 1);
    OSTEP(0);
    __syncthreads();
    if (k0 + 64 < Kd) OPRE(k0 + 64, 0);
    OSTEP(1);
    __syncthreads();
  }
#undef OPRE
#undef OSTEP

#pragma unroll
  for (int j = 0; j < 4; ++j) {
    const int col = nb + wc + j * 16 + m16;
    const float bv = bias[col];
#pragma unroll
    for (int i = 0; i < 2; ++i)
#pragma unroll
      for (int r = 0; r < 4; ++r) {
        const int row = mb + wr + i * 16 + quad * 4 + r;
        Outp[(size_t)row * 1024 + col] = acc[i][j][r] + bv;
      }
  }
}

// -------- flash attention v12: QBLK=64 per wave (2 q-tiles share every K/V LDS
//          read -> per-q LDS traffic HALVED vs v10). 32x32 swapped-QKT,
//          in-register P. 8 waves/block: wq in 0..3 gives q sub-range,
//          half = w>>2 gives kv half (in-block kv-split as v10b).
//          Block covers 256 q x full kv. 256 blocks = 1/CU. ----------------------
__global__ __launch_bounds__(512) void flash_attn(
    const u16* __restrict__ Q, const u16* __restrict__ K, const u16* __restrict__ Vt,
    u16* __restrict__ O)
{
  const int S = 2048;
  // staging: K 2half x 2buf x 4096 u16, then V same = 64KB.
  // combine region (after main loop) overlays: 16896 f32 = 67584B -> SH 33792 u16.
  __shared__ __align__(16) u16 SH[33792];
  u16* const KlF = SH;
  u16* const VlF = SH + 16384;
  const int t = threadIdx.x;
  const int lane = t & 63, w = t >> 6;
  const int l31 = lane & 31, hi = lane >> 5;
  const int wq = w & 3;                  // q sub-tile (64 q each)
  const int half = w >> 2;               // kv half: 0 -> [0,1024), 1 -> [1024,2048)
  const int hoff = half * 8192;          // LDS offset of this half's region (u16)

  const int f = blockIdx.x;              // 256 blocks
  const int wi = f >> 3;                 // 0..31
  const int bh = (f & 7) + 8 * (wi & 3); // consecutive blocks -> different heads
  const int q0 = (wi >> 2) * 256;        // 8 q-groups of 256

  const u16* Qb = Q + (size_t)bh * S * 64;
  const u16* Kb = K + (size_t)bh * S * 64;
  const u16* Vb = Vt + (size_t)bh * 64 * S;

  // Q fragments for both q-tiles: B[n=q][k=d], lane n=l31, d = dc*16 + hi*8 + e
  bf16x8 qf0[4], qf1[4];
#pragma unroll
  for (int dc = 0; dc < 4; ++dc) {
    qf0[dc] = *(const bf16x8*)(Qb + (size_t)(q0 + wq * 64 + l31) * 64 + dc * 16 + hi * 8);
    qf1[dc] = *(const bf16x8*)(Qb + (size_t)(q0 + wq * 64 + 32 + l31) * 64 + dc * 16 + hi * 8);
  }

  // staging: each half's 4 waves stage their own kv range.
  // pre-swizzled global source, linear LDS dest (slot ^= row&7).
  const int tidx = t & 255;
  const u16* Kg[2]; const u16* Vg[2]; int soff[2];
#pragma unroll
  for (int l = 0; l < 2; ++l) {
    const int idx = l * 256 + tidx;
    const int row = idx >> 3, slot = idx & 7;
    const int sg = slot ^ (row & 7);
    Kg[l] = Kb + (size_t)(half * 1024 + row) * 64 + sg * 8;
    Vg[l] = Vb + (size_t)row * S + half * 1024 + sg * 8;
    soff[l] = idx * 8;
  }

  f32x16 ot[2][2] = {};                  // [qt][dt]
  float lr0[4] = {0.f, 0.f, 0.f, 0.f};
  float lr1[4] = {0.f, 0.f, 0.f, 0.f};

#define PRE(tile, B)                                                         \
  do {                                                                       \
    _Pragma("unroll")                                                        \
    for (int l = 0; l < 2; ++l)                                              \
      async_load16(Kg[l] + (size_t)(tile) * 4096, KlF + hoff + (B) * 4096 + soff[l]); \
    _Pragma("unroll")                                                        \
    for (int l = 0; l < 2; ++l)                                              \
      async_load16(Vg[l] + (tile) * 64, VlF + hoff + (B) * 4096 + soff[l]);  \
  } while (0)

#define STEP(B)                                                              \
  do {                                                                       \
    const u16* kb_ = KlF + hoff + (B) * 4096;                                \
    const u16* vb_ = VlF + hoff + (B) * 4096;                                \
    bf16x8 pa0[4], pa1[4];                                                   \
    _Pragma("unroll")                                                        \
    for (int kt = 0; kt < 2; ++kt) {                                         \
      f32x16 s0 = {0.f,0.f,0.f,0.f, 0.f,0.f,0.f,0.f,                         \
                   0.f,0.f,0.f,0.f, 0.f,0.f,0.f,0.f};                        \
      f32x16 s1 = s0;                                                        \
      const int kvr = kt * 32 + l31;                                         \
      const u16* krow = kb_ + kvr * 64;                                      \
      _Pragma("unroll")                                                      \
      for (int dc = 0; dc < 4; ++dc) {                                       \
        const bf16x8 kb = *(const bf16x8*)(krow + (((dc * 2 + hi) ^ (kvr & 7)) * 8)); \
        s0 = __builtin_amdgcn_mfma_f32_32x32x16_bf16(kb, qf0[dc], s0, 0, 0, 0); \
        s1 = __builtin_amdgcn_mfma_f32_32x32x16_bf16(kb, qf1[dc], s1, 0, 0, 0); \
      }                                                                      \
      float p[16];                                                           \
      _Pragma("unroll")                                                      \
      for (int r = 0; r < 16; ++r) { p[r] = EXP2(s0[r]); lr0[r & 3] += p[r]; } \
      _Pragma("unroll")                                                      \
      for (int cc = 0; cc < 2; ++cc) {                                       \
        union { u32 u[4]; bf16x8 v; } fr;                                    \
        _Pragma("unroll")                                                    \
        for (int i = 0; i < 2; ++i) {                                        \
          const u32 xx = pk_bf16(p[8 * cc + 2 * i + 0], p[8 * cc + 2 * i + 1]); \
          const u32 yy = pk_bf16(p[8 * cc + 2 * i + 4], p[8 * cc + 2 * i + 5]); \
          u32 r0, r1;                                                        \
          plane32swap(xx, yy, r0, r1);                                       \
          fr.u[i] = r0; fr.u[2 + i] = r1;                                    \
        }                                                                    \
        pa0[kt * 2 + cc] = fr.v;                                             \
      }                                                                      \
      _Pragma("unroll")                                                      \
      for (int r = 0; r < 16; ++r) { p[r] = EXP2(s1[r]); lr1[r & 3] += p[r]; } \
      _Pragma("unroll")                                                      \
      for (int cc = 0; cc < 2; ++cc) {                                       \
        union { u32 u[4]; bf16x8 v; } fr;                                    \
        _Pragma("unroll")                                                    \
        for (int i = 0; i < 2; ++i) {                                        \
          const u32 xx = pk_bf16(p[8 * cc + 2 * i + 0], p[8 * cc + 2 * i + 1]); \
          const u32 yy = pk_bf16(p[8 * cc + 2 * i + 4], p[8 * cc + 2 * i + 5]); \
          u32 r0, r1;                                                        \
          plane32swap(xx, yy, r0, r1);                                       \
          fr.u[i] = r0; fr.u[2 + i] = r1;                                    \
        }                                                                    \
        pa1[kt * 2 + cc] = fr.v;                                             \
      }                                                                      \
    }                                                                        \
    _Pragma("unroll")                                                        \
    for (int c = 0; c < 4; ++c) {                                            \
      _Pragma("unroll")                                                      \
      for (int dt = 0; dt < 2; ++dt) {                                       \
        const int dr = dt * 32 + l31;                                        \
        const bf16x8 va = *(const bf16x8*)(vb_ + dr * 64 + (((c * 2 + hi) ^ (dr & 7)) * 8)); \
        ot[0][dt] = __builtin_amdgcn_mfma_f32_32x32x16_bf16(va, pa0[c], ot[0][dt], 0, 0, 0); \
        ot[1][dt] = __builtin_amdgcn_mfma_f32_32x32x16_bf16(va, pa1[c], ot[1][dt], 0, 0, 0); \
      }                                                                      \
    }                                                                        \
  } while (0)

  PRE(0, 0);
  __syncthreads();

  for (int tp = 0; tp < 16; tp += 2) {
    PRE(tp + 1, 1);
    STEP(0);
    __syncthreads();
    if (tp + 2 < 16) PRE(tp + 2, 0);
    STEP(1);
    __syncthreads();
  }
#undef PRE
#undef STEP

  // per-qt softmax denominators (hi-halves hold complementary kv subsets)
  float l0 = lr0[0] + lr0[1] + lr0[2] + lr0[3];
  float l1 = lr1[0] + lr1[1] + lr1[2] + lr1[3];
  l0 += __shfl_xor(l0, 32, 64);
  l1 += __shfl_xor(l1, 32, 64);

  // ---- cross-half combine via LDS (staging buffers dead past the last barrier) --
  // Opart: wq*4096 + (qt*32 + dt*16 + r)*64 + lane   (4 wq x 4096 f32 = 16384)
  // l:     16384 + wq*128 + qt*64 + lane
  float* const smemF = (float*)SH;       // uses 16896 f32 = 67584 B (SH = 33792 u16)
  if (half == 1) {
#pragma unroll
    for (int qt = 0; qt < 2; ++qt)
#pragma unroll
      for (int dt = 0; dt < 2; ++dt)
#pragma unroll
        for (int r = 0; r < 16; ++r)
          smemF[wq * 4096 + (qt * 32 + dt * 16 + r) * 64 + lane] = ot[qt][dt][r];
    smemF[16384 + wq * 128 + lane] = l0;        // qt=0 slots [0,64)
    smemF[16384 + wq * 128 + 64 + (lane & 63) * 0 + lane] = l1;  // qt=1 slots [64,128)
  }
  __syncthreads();
  if (half == 0) {
    l0 += smemF[16384 + wq * 128 + lane];
    l1 += smemF[16384 + wq * 128 + 64 + lane];
#pragma unroll
    for (int qt = 0; qt < 2; ++qt)
#pragma unroll
      for (int dt = 0; dt < 2; ++dt)
#pragma unroll
        for (int r = 0; r < 16; ++r)
          ot[qt][dt][r] += smemF[wq * 4096 + (qt * 32 + dt * 16 + r) * 64 + lane];

    const int b = bh >> 4, h = bh & 15;
    const float inv0 = 1.0f / l0;
    const float inv1 = 1.0f / l1;
#pragma unroll
    for (int qt = 0; qt < 2; ++qt) {
      const float inv = qt ? inv1 : inv0;
      const int q = q0 + wq * 64 + qt * 32 + l31;
      u16* base = O + ((size_t)b * 2048 + q) * 1024 + h * 64;
#pragma unroll
      for (int dt = 0; dt < 2; ++dt)
#pragma unroll
        for (int g4 = 0; g4 < 4; ++g4) {
          // reg r=4*g4+j -> d = dt*32 + 8*g4 + 4*hi + j
          const u32 lo = pk_bf16(ot[qt][dt][4 * g4 + 0] * inv, ot[qt][dt][4 * g4 + 1] * inv);
          const u32 h2 = pk_bf16(ot[qt][dt][4 * g4 + 2] * inv, ot[qt][dt][4 * g4 + 3] * inv);
          *(uint2*)(base + dt * 32 + 8 * g4 + 4 * hi) = make_uint2(lo, h2);
        }
    }
  }
}

// ---------------- launch ----------------
extern "C" void kernel_launch(void* const* d_in, const int* in_sizes, int n_in,
                              void* d_out, int out_size, void* d_ws, size_t ws_size,
                              hipStream_t stream)
{
  const float* x     = (const float*)d_in[0];   // [2,2048,1024] f32
  const float* w_qkv = (const float*)d_in[1];   // [1024,3072]  f32
  const float* b_qkv = (const float*)d_in[2];   // [3072]       f32
  const float* w_out = (const float*)d_in[3];   // [1024,1024]  f32
  const float* b_out = (const float*)d_in[4];   // [1024]       f32
  float* out = (float*)d_out;                   // [2,2048,1024] f32

  u16* ws     = (u16*)d_ws;
  u16* xb     = ws;                          // [4096][1024] bf16
  u16* WtQKV  = xb + 4194304;                // [3072][1024] bf16
  u16* WtOut  = WtQKV + 3145728;             // [1024][1024] bf16
  u16* Qm     = WtOut + 1048576;             // [B,H,S,64]
  u16* Km     = Qm + 4194304;                // [B,H,S,64]
  u16* Vtm    = Km + 4194304;                // [B,H,64,S]  (written directly by gemm_qkv)
  u16* AO     = Vtm + 4194304;               // [B,S,E] bf16

  preprocess<<<3072, 256, 0, stream>>>(x, xb, w_qkv, WtQKV, w_out, WtOut);
  gemm_qkv<<<dim3(24, 32), 256, 0, stream>>>(xb, WtQKV, b_qkv, Qm, Km, Vtm);
  flash_attn<<<256, 512, 0, stream>>>(Qm, Km, Vtm, AO);
  gemm_out<<<dim3(8, 64), 256, 0, stream>>>(AO, WtOut, b_out, out);
}